// Round 4
// baseline (377.152 us; speedup 1.0000x reference)
//
#include <hip/hip_runtime.h>
#include <math.h>
#include <limits.h>

#define M_ROWS 65536   // B*N = 64*1024
#define DD     256     // feature dim
#define KC     512     // codes
#define TILE_M 128     // rows per block
#define CHUNK  128     // codes per chunk
#define KS     32      // k-slice (floats) staged in LDS

// numpy-style pairwise sum (8 accumulators, block 128) of squares of 128 floats.
__device__ __forceinline__ float pw128_sq(const float4* __restrict__ q) {
  float r[8];
  {
    float4 a = q[0], b = q[1];
    r[0] = __fmul_rn(a.x, a.x); r[1] = __fmul_rn(a.y, a.y);
    r[2] = __fmul_rn(a.z, a.z); r[3] = __fmul_rn(a.w, a.w);
    r[4] = __fmul_rn(b.x, b.x); r[5] = __fmul_rn(b.y, b.y);
    r[6] = __fmul_rn(b.z, b.z); r[7] = __fmul_rn(b.w, b.w);
  }
#pragma unroll
  for (int i = 2; i < 32; i += 2) {
    float4 a = q[i], b = q[i + 1];
    r[0] = __fadd_rn(r[0], __fmul_rn(a.x, a.x));
    r[1] = __fadd_rn(r[1], __fmul_rn(a.y, a.y));
    r[2] = __fadd_rn(r[2], __fmul_rn(a.z, a.z));
    r[3] = __fadd_rn(r[3], __fmul_rn(a.w, a.w));
    r[4] = __fadd_rn(r[4], __fmul_rn(b.x, b.x));
    r[5] = __fadd_rn(r[5], __fmul_rn(b.y, b.y));
    r[6] = __fadd_rn(r[6], __fmul_rn(b.z, b.z));
    r[7] = __fadd_rn(r[7], __fmul_rn(b.w, b.w));
  }
  return __fadd_rn(__fadd_rn(__fadd_rn(r[0], r[1]), __fadd_rn(r[2], r[3])),
                   __fadd_rn(__fadd_rn(r[4], r[5]), __fadd_rn(r[6], r[7])));
}

__global__ void sumsq_kernel(const float* __restrict__ x, float* __restrict__ s,
                             int nrows) {
  int r = blockIdx.x * blockDim.x + threadIdx.x;
  if (r >= nrows) return;
  const float4* q = (const float4*)(x + (size_t)r * DD);
  s[r] = __fadd_rn(pw128_sq(q), pw128_sq(q + 32));
}

// async global->LDS, 16B per lane: LDS dest = wave-uniform base + lane*16
typedef __attribute__((address_space(1))) const void gas_void;
typedef __attribute__((address_space(3))) void las_void;
__device__ __forceinline__ void gl_lds16(const void* g, void* l) {
  __builtin_amdgcn_global_load_lds((gas_void*)g, (las_void*)l, 16, 0, 0);
}

// Swizzle: float4-column q of row r lives at LDS slot (r<<3) | (q ^ ((r>>3)&7)).
// global_load_lds writes LDS linearly, so the SOURCE address is inverse-swizzled:
// for linear slot u: row=u>>3, qs=u&7, q = qs ^ ((row>>3)&7).
__global__ __launch_bounds__(256) void vq_kernel(
    const float* __restrict__ z, const float* __restrict__ cb,
    const float* __restrict__ s, const float* __restrict__ se,
    float* __restrict__ out) {
  __shared__ float4 zs4[2][TILE_M * 8];  // 2 x 16 KB
  __shared__ float4 es4[2][CHUNK * 8];   // 2 x 16 KB   => exactly 64 KB

  const int tid = threadIdx.x;
  const int tx = tid & 15, ty = tid >> 4;
  const int txs = tx & 7, tys = ty & 7;
  const int wv = tid >> 6;     // wave 0..3
  const int lane = tid & 63;
  const int r0 = blockIdx.x * TILE_M;

  const float4* zg = (const float4*)z;
  const float4* cg = (const float4*)cb;

  // per-thread ||z||^2 for its 8 rows (registers; LDS is fully used by tiles)
  float s_reg[8];
#pragma unroll
  for (int i = 0; i < 8; ++i) s_reg[i] = s[r0 + ty * 8 + i];

  float bestd[8];
  int   besti[8];
#pragma unroll
  for (int i = 0; i < 8; ++i) { bestd[i] = INFINITY; besti[i] = INT_MAX; }

  // stage one 16KB slice (z or e) into buffer b; 4 waves x 4 segs x 1KB
  auto stage_z = [&](int b, int ks) {
#pragma unroll
    for (int seg = 0; seg < 4; ++seg) {
      int u = (wv * 4 + seg) * 64 + lane;        // linear slot
      int row = u >> 3, qs = u & 7;
      int q = qs ^ ((row >> 3) & 7);
      gl_lds16(&zg[(size_t)(r0 + row) * 64 + ks * 8 + q],
               (char*)&zs4[b][0] + (wv * 4 + seg) * 1024);
    }
  };
  auto stage_e = [&](int b, int cbase, int ks) {
#pragma unroll
    for (int seg = 0; seg < 4; ++seg) {
      int u = (wv * 4 + seg) * 64 + lane;
      int row = u >> 3, qs = u & 7;
      int q = qs ^ ((row >> 3) & 7);
      gl_lds16(&cg[(size_t)(cbase + row) * 64 + ks * 8 + q],
               (char*)&es4[b][0] + (wv * 4 + seg) * 1024);
    }
  };

  auto compute = [&](int b, float (&acc)[8][8]) {
#pragma unroll
    for (int k4 = 0; k4 < 8; ++k4) {
      const float4* zp = &zs4[b][ty * 64 + (k4 ^ tys)];
      const float4* ep = &es4[b][tx * 64 + (k4 ^ txs)];
      float4 zf[8];
#pragma unroll
      for (int i = 0; i < 8; ++i) zf[i] = zp[i * 8];
#pragma unroll
      for (int j = 0; j < 8; ++j) {
        float4 ef = ep[j * 8];
        // strict k-ascending FMA chain per (row, code) — bit-identical to ref
#pragma unroll
        for (int i = 0; i < 8; ++i) {
          acc[i][j] = __fmaf_rn(zf[i].x, ef.x, acc[i][j]);
          acc[i][j] = __fmaf_rn(zf[i].y, ef.y, acc[i][j]);
          acc[i][j] = __fmaf_rn(zf[i].z, ef.z, acc[i][j]);
          acc[i][j] = __fmaf_rn(zf[i].w, ef.w, acc[i][j]);
        }
      }
    }
  };

#pragma unroll 1
  for (int ch = 0; ch < KC / CHUNK; ++ch) {
    const int cbase = ch * CHUNK;
    float se_reg[8];
#pragma unroll
    for (int j = 0; j < 8; ++j) se_reg[j] = se[cbase + tx * 8 + j];

    float acc[8][8];
#pragma unroll
    for (int i = 0; i < 8; ++i)
#pragma unroll
      for (int j = 0; j < 8; ++j) acc[i][j] = 0.0f;

    stage_z(0, 0);
    stage_e(0, cbase, 0);
    __syncthreads();               // compiler drains vmcnt here (prologue only)

    int b = 0;
#pragma unroll 1
    for (int ks = 0; ks < DD / KS; ++ks) {   // 8 slices
      if (ks < DD / KS - 1) {                // issue next slice (in flight
        stage_z(b ^ 1, ks + 1);              //  under ~4100 cyc of FMAs)
        stage_e(b ^ 1, cbase, ks + 1);
      }
      compute(b, acc);
      __syncthreads();             // single barrier/slice; vmcnt auto-drained
      b ^= 1;
    }

    // d = (s - 2*dot) + se, rounded exactly like the reference expression
#pragma unroll
    for (int i = 0; i < 8; ++i) {
#pragma unroll
      for (int j = 0; j < 8; ++j) {
        int code = cbase + tx * 8 + j;
        float d = __fadd_rn(__fsub_rn(s_reg[i], __fmul_rn(2.0f, acc[i][j])),
                            se_reg[j]);
        if (d < bestd[i] || (d == bestd[i] && code < besti[i])) {
          bestd[i] = d; besti[i] = code;
        }
      }
    }
    // loop's final __syncthreads already separates this chunk's reads from
    // the next chunk's stage into buffer 0
  }

  // argmin reduce across the 16 tx lanes (same wave), min-d then min-index
  int* best_l = (int*)&zs4[0][0];  // alias dead tile memory (post-barrier)
#pragma unroll
  for (int i = 0; i < 8; ++i) {
    float bd = bestd[i];
    int   bi = besti[i];
#pragma unroll
    for (int off = 1; off < 16; off <<= 1) {
      float od = __shfl_xor(bd, off, 64);
      int   oi = __shfl_xor(bi, off, 64);
      if (od < bd || (od == bd && oi < bi)) { bd = od; bi = oi; }
    }
    if (tx == 0) best_l[ty * 8 + i] = bi;
  }
  __syncthreads();

  // epilogue: out0 = fl(z + fl(cb[idx]-z)), out1 = cb[idx]
  float4* out0 = (float4*)out;
  float4* out1 = (float4*)(out + (size_t)M_ROWS * DD);
#pragma unroll
  for (int it = 0; it < (TILE_M * 64) / 256; ++it) {
    int u = it * 256 + tid;
    int row = u >> 6, c4 = u & 63;
    size_t gidx = (size_t)(r0 + row) * 64 + c4;
    float4 zv = zg[gidx];
    float4 cv = cg[(size_t)best_l[row] * 64 + c4];
    float4 o0;
    o0.x = __fadd_rn(zv.x, __fsub_rn(cv.x, zv.x));
    o0.y = __fadd_rn(zv.y, __fsub_rn(cv.y, zv.y));
    o0.z = __fadd_rn(zv.z, __fsub_rn(cv.z, zv.z));
    o0.w = __fadd_rn(zv.w, __fsub_rn(cv.w, zv.w));
    out0[gidx] = o0;
    out1[gidx] = cv;
  }
}

extern "C" void kernel_launch(void* const* d_in, const int* in_sizes, int n_in,
                              void* d_out, int out_size, void* d_ws, size_t ws_size,
                              hipStream_t stream) {
  const float* z  = (const float*)d_in[0];   // [65536, 256]
  const float* cb = (const float*)d_in[1];   // [512, 256]
  float* out = (float*)d_out;                // 2 x [65536, 256] concat
  float* s  = (float*)d_ws;                  // ||z||^2 per row
  float* se = s + M_ROWS;                    // ||e||^2 per code

  sumsq_kernel<<<M_ROWS / 256, 256, 0, stream>>>(z, s, M_ROWS);
  sumsq_kernel<<<KC / 256, 256, 0, stream>>>(cb, se, KC);
  vq_kernel<<<M_ROWS / TILE_M, 256, 0, stream>>>(z, cb, s, se, out);
}